// Round 4
// baseline (188.249 us; speedup 1.0000x reference)
//
#include <hip/hip_runtime.h>
#include <stdint.h>

typedef __attribute__((ext_vector_type(8))) short short8;
typedef __attribute__((ext_vector_type(4))) float f32x4;
typedef __attribute__((ext_vector_type(16))) float f32x16;
typedef __attribute__((ext_vector_type(4))) unsigned short ushort4v;
typedef __attribute__((ext_vector_type(2))) int int2v;

#define BB 2
#define SS 2048
#define NXDIM 1024
#define NHEADS 16
#define HDIM 64

__device__ __forceinline__ unsigned short f2bf(float f){
  unsigned int u = __float_as_uint(f);
  u += 0x7fffu + ((u >> 16) & 1u);
  return (unsigned short)(u >> 16);
}

__device__ __forceinline__ void gload_lds16(const void* g, void* l){
  __builtin_amdgcn_global_load_lds((const __attribute__((address_space(1))) void*)g,
                                   (__attribute__((address_space(3))) void*)l, 16, 0, 0);
}

__device__ __forceinline__ unsigned cvt_pk_bf16(float lo, float hi){
  unsigned r;
  asm("v_cvt_pk_bf16_f32 %0, %1, %2" : "=v"(r) : "v"(lo), "v"(hi));
  return r;
}

__device__ __forceinline__ int2v ds_tr_b16(unsigned addr){
  int2v r;
  asm volatile("ds_read_b64_tr_b16 %0, %1" : "=v"(r) : "v"(addr));
  return r;
}

// ---------------- f32 -> bf16 convert (vectorized) ----------------
__global__ __launch_bounds__(256) void f32_to_bf16_k(const float* __restrict__ in,
                                                     unsigned short* __restrict__ out, int n4){
  int i = blockIdx.x * 256 + threadIdx.x;
  if (i >= n4) return;
  float4 v = ((const float4*)in)[i];
  ushort4v r = { f2bf(v.x), f2bf(v.y), f2bf(v.z), f2bf(v.w) };
  ((ushort4v*)out)[i] = r;
}

// ---------------- f32 [R][C] -> bf16 transposed [C][R] ----------------
__global__ __launch_bounds__(256) void transpose_bf16_k(const float* __restrict__ in,
                                                        unsigned short* __restrict__ out,
                                                        int R, int C){
  __shared__ float t[32][33];
  const int bx = blockIdx.x * 32, by = blockIdx.y * 32;
  const int tx = threadIdx.x, ty = threadIdx.y;
  #pragma unroll
  for (int i = ty; i < 32; i += 8)
    t[i][tx] = in[(size_t)(by + i) * C + bx + tx];
  __syncthreads();
  #pragma unroll
  for (int i = ty; i < 32; i += 8)
    out[(size_t)(bx + i) * R + by + tx] = f2bf(t[tx][i]);
}

// ---------------- bf16 GEMM: C[M,N] = A[M,K] * BT[N,K]^T + bias ----------------
template<bool OUT_F32>
__global__ __launch_bounds__(256) void gemm_bt_k(const unsigned short* __restrict__ A,
                                                 const unsigned short* __restrict__ BT,
                                                 const float* __restrict__ bias,
                                                 void* __restrict__ Cout,
                                                 int M, int N, int K)
{
  __shared__ unsigned short As[128*32];
  __shared__ unsigned short Bs[128*32];
  const int tid = threadIdx.x;
  const int w = tid >> 6, lane = tid & 63;
  const int l15 = lane & 15, g = lane >> 4;
  const int wr = w >> 1, wc = w & 1;
  const int m0 = blockIdx.y * 128, n0 = blockIdx.x * 128;

  f32x4 acc[4][4];
  #pragma unroll
  for (int m=0;m<4;m++)
    #pragma unroll
    for (int n=0;n<4;n++) acc[m][n] = (f32x4){0.f,0.f,0.f,0.f};

  const int scol = (lane & 3) * 8;

  for (int k0 = 0; k0 < K; k0 += 32){
    __syncthreads();
    #pragma unroll
    for (int j=0;j<2;j++){
      const int row = w*32 + j*16 + (lane >> 2);
      const unsigned short* ga = A  + (size_t)(m0 + row) * K + (k0 + scol);
      const unsigned short* gb = BT + (size_t)(n0 + row) * K + (k0 + scol);
      gload_lds16(ga, &As[(w*32 + j*16) * 32]);
      gload_lds16(gb, &Bs[(w*32 + j*16) * 32]);
    }
    __syncthreads();

    short8 af[4], bf[4];
    #pragma unroll
    for (int m=0;m<4;m++) af[m] = *(const short8*)&As[(wr*64 + m*16 + l15)*32 + g*8];
    #pragma unroll
    for (int n=0;n<4;n++) bf[n] = *(const short8*)&Bs[(wc*64 + n*16 + l15)*32 + g*8];
    #pragma unroll
    for (int m=0;m<4;m++)
      #pragma unroll
      for (int n=0;n<4;n++)
        acc[m][n] = __builtin_amdgcn_mfma_f32_16x16x32_bf16(af[m], bf[n], acc[m][n], 0, 0, 0);
  }

  const int crow0 = m0 + wr*64;
  const int ccol0 = n0 + wc*64;
  #pragma unroll
  for (int n=0;n<4;n++){
    const int col = ccol0 + n*16 + l15;
    const float bv = bias[col];
    #pragma unroll
    for (int m=0;m<4;m++){
      #pragma unroll
      for (int r=0;r<4;r++){
        const int row = crow0 + m*16 + g*4 + r;
        const float v = acc[m][n][r] + bv;
        if (OUT_F32) ((float*)Cout)[(size_t)row * N + col] = v;
        else         ((unsigned short*)Cout)[(size_t)row * N + col] = f2bf(v);
      }
    }
  }
}

// ---------------- causal flash attention, swapped-operand 32x32 MFMA ----------------
// 128 threads = 2 waves; wave w owns q rows [qb*64+w*32, +32). KV tile = 64, double-buffered.
// S^T = mfma(K, Q^T): col=q(lane&31), row=kv((r&3)+8*(r>>2)+4*hi) -> in-register softmax (exp2 domain).
// Lane exchanges via __shfl_xor(.,32) (verified round-2 forms).
__global__ __launch_bounds__(128) void attn_k(const unsigned short* __restrict__ qkv,
                                              unsigned short* __restrict__ aout)
{
  const int qb = (int)gridDim.x - 1 - (int)blockIdx.x;   // heavy tiles first
  const int h = blockIdx.y, b = blockIdx.z;
  const int tid = threadIdx.x;
  const int w = tid >> 6, lane = tid & 63;
  const int l31 = lane & 31, hi = lane >> 5;

  __shared__ unsigned short Ks[2][64*64];   // [kv][d] XOR-swizzled rows (byte ^= (row&7)<<4)
  __shared__ unsigned short Vs[2][64*64];   // subtiled for ds_read_b64_tr_b16

  const size_t rs = 3 * NXDIM;
  const unsigned short* Qg = qkv + (size_t)b * SS * rs + h * HDIM;
  const unsigned short* Kg = Qg + NXDIM;
  const unsigned short* Vg = Qg + 2 * NXDIM;

  const int q0w = qb*64 + w*32;
  const int q   = q0w + l31;
  const int qw_hi = q0w + 31;

  short8 qf[4];
  #pragma unroll
  for (int c=0;c<4;c++)
    qf[c] = *(const short8*)(Qg + (size_t)q * rs + c*16 + 8*hi);

  f32x16 O0, O1;
  #pragma unroll
  for (int r=0;r<16;r++){ O0[r]=0.f; O1[r]=0.f; }
  float m_run = -1e30f, l_run = 0.f;
  const float SC2 = 0.125f * 1.44269504089f;   // scale * log2(e)

  // staging source coords
  const int krow_in = lane >> 3;
  const int kcol    = 8 * ((lane & 7) ^ (lane >> 3));
  const int v_d     = ((lane >> 3) & 3) * 16 + 8 * (lane & 1);
  const unsigned vtr_base = (unsigned)(size_t)&Vs[0][0] + 8u*(unsigned)lane + 768u*(unsigned)hi;

  // stage tile t (64 kv rows) into buffer bi: 8 chunks, 4 per wave
  auto stage = [&](int bi, int tt){
    #pragma unroll
    for (int j=0;j<4;j++){
      const int ch = w*4 + j;
      const int krow = tt*64 + ch*8 + krow_in;
      gload_lds16(Kg + (size_t)krow * rs + kcol, &Ks[bi][ch*512]);
      const int vkv = tt*64 + (ch*2 + hi)*4 + ((lane>>1)&3);
      gload_lds16(Vg + (size_t)vkv * rs + v_d, &Vs[bi][ch*512]);
    }
  };

  stage(0, 0);
  __syncthreads();
  int cur = 0;

  for (int t = 0; t <= qb; ++t){
    if (t < qb) stage(cur^1, t+1);          // prefetch next tile (hides under compute)

    const char* Kb = (const char*)&Ks[cur][0];
    const unsigned vb = vtr_base + (unsigned)(cur * 8192);

    #pragma unroll
    for (int kvs=0;kvs<2;kvs++){
      const int kv_lo = t*64 + kvs*32;
      if (kv_lo > qw_hi) continue;          // wave-uniform skip (fully masked)

      // ---- S^T = K * Q^T ----
      f32x16 S;
      #pragma unroll
      for (int r=0;r<16;r++) S[r] = 0.f;
      __builtin_amdgcn_s_setprio(1);
      #pragma unroll
      for (int c=0;c<4;c++){
        const int row = kvs*32 + l31;
        short8 kf = *(const short8*)(Kb + row*128 + ((c*32 + 16*hi) ^ ((row&7)<<4)));
        S = __builtin_amdgcn_mfma_f32_32x32x16_bf16(kf, qf[c], S, 0, 0, 0);
      }
      __builtin_amdgcn_s_setprio(0);

      // ---- online softmax, exp2 domain (per-lane column q) ----
      float mx = -1e30f;
      if (kv_lo + 31 > q0w){
        #pragma unroll
        for (int r=0;r<16;r++){
          const int kv = kv_lo + (r&3) + 8*(r>>2) + 4*hi;
          float sv = (kv <= q) ? S[r]*SC2 : -1e30f;
          S[r] = sv; mx = fmaxf(mx, sv);
        }
      } else {
        #pragma unroll
        for (int r=0;r<16;r++){ float sv = S[r]*SC2; S[r] = sv; mx = fmaxf(mx, sv); }
      }
      mx = fmaxf(mx, __shfl_xor(mx, 32));
      const float m_new = fmaxf(m_run, mx);
      const float corr = __builtin_exp2f(m_run - m_new);
      m_run = m_new;
      float ls = 0.f;
      #pragma unroll
      for (int r=0;r<16;r++){ const float p = __builtin_exp2f(S[r] - m_new); S[r] = p; ls += p; }
      ls += __shfl_xor(ls, 32);
      l_run = l_run * corr + ls;
      #pragma unroll
      for (int r=0;r<16;r++){ O0[r] *= corr; O1[r] *= corr; }

      // ---- P^T -> bf16 fragment via cvt_pk + shfl_xor half-exchange (verified) ----
      unsigned pk[8], xk[8];
      #pragma unroll
      for (int i=0;i<8;i++) pk[i] = cvt_pk_bf16(S[2*i], S[2*i+1]);
      #pragma unroll
      for (int i=0;i<8;i++) xk[i] = (unsigned)__shfl_xor((int)pk[i], 32);
      short8 pfrag[2];
      #pragma unroll
      for (int c=0;c<2;c++){
        union { unsigned u[4]; short8 s; } pw;
        pw.u[0] = hi ? xk[4*c+2] : pk[4*c+0];
        pw.u[1] = hi ? xk[4*c+3] : pk[4*c+1];
        pw.u[2] = hi ? pk[4*c+2] : xk[4*c+0];
        pw.u[3] = hi ? pk[4*c+3] : xk[4*c+1];
        pfrag[c] = pw.s;
      }

      // ---- V^T fragments via ds_read_b64_tr_b16, then O^T += V^T * P^T ----
      int2v tv[8];
      #pragma unroll
      for (int c=0;c<2;c++)
        #pragma unroll
        for (int dh=0;dh<2;dh++)
          #pragma unroll
          for (int eb=0;eb<2;eb++)
            tv[c*4+dh*2+eb] = ds_tr_b16(vb + (unsigned)((kvs*8 + c*4 + eb)*512 + dh*256));
      asm volatile("s_waitcnt lgkmcnt(0)" ::: "memory");
      __builtin_amdgcn_sched_barrier(0);

      __builtin_amdgcn_s_setprio(1);
      #pragma unroll
      for (int c=0;c<2;c++){
        union { int2v t[2]; short8 s; } v0, v1;
        v0.t[0] = tv[c*4+0]; v0.t[1] = tv[c*4+1];
        v1.t[0] = tv[c*4+2]; v1.t[1] = tv[c*4+3];
        O0 = __builtin_amdgcn_mfma_f32_32x32x16_bf16(v0.s, pfrag[c], O0, 0, 0, 0);
        O1 = __builtin_amdgcn_mfma_f32_32x32x16_bf16(v1.s, pfrag[c], O1, 0, 0, 0);
      }
      __builtin_amdgcn_s_setprio(0);
    }

    __syncthreads();   // drains prefetch (vmcnt) + protects buffer reuse
    cur ^= 1;
  }

  // ---- epilogue: O^T /= l, write aout[b][q][h*64 + d] ----
  const float inv = 1.f / l_run;
  unsigned short* dst = aout + ((size_t)b*SS + q) * NXDIM + h*HDIM;
  #pragma unroll
  for (int g4=0; g4<4; g4++){
    ushort4v a0, a1;
    #pragma unroll
    for (int i=0;i<4;i++){ a0[i] = f2bf(O0[4*g4+i]*inv); a1[i] = f2bf(O1[4*g4+i]*inv); }
    *(ushort4v*)(dst + 8*g4 + 4*hi)      = a0;
    *(ushort4v*)(dst + 32 + 8*g4 + 4*hi) = a1;
  }
}

extern "C" void kernel_launch(void* const* d_in, const int* in_sizes, int n_in,
                              void* d_out, int out_size, void* d_ws, size_t ws_size,
                              hipStream_t stream){
  (void)in_sizes; (void)n_in; (void)out_size; (void)ws_size;
  const float* x      = (const float*)d_in[0];   // [2,2048,1024]
  const float* w_attn = (const float*)d_in[1];   // [1024,3072]
  const float* b_attn = (const float*)d_in[2];   // [3072]
  const float* w_proj = (const float*)d_in[3];   // [1024,1024]
  const float* b_proj = (const float*)d_in[4];   // [1024]
  float* out = (float*)d_out;                    // [2,2048,1024] f32

  unsigned short* xb   = (unsigned short*)d_ws;              // 4096x1024 bf16
  unsigned short* waT  = xb  + (size_t)4096*1024;            // 3072x1024 bf16 (W_attn^T)
  unsigned short* wpT  = waT + (size_t)3072*1024;            // 1024x1024 bf16 (W_proj^T)
  unsigned short* qkv  = wpT + (size_t)1024*1024;            // 4096x3072 bf16
  unsigned short* aout = qkv + (size_t)4096*3072;            // 4096x1024 bf16

  f32_to_bf16_k<<<4096, 256, 0, stream>>>(x, xb, 4096*1024/4);
  transpose_bf16_k<<<dim3(3072/32, 1024/32), dim3(32,8), 0, stream>>>(w_attn, waT, 1024, 3072);
  transpose_bf16_k<<<dim3(1024/32, 1024/32), dim3(32,8), 0, stream>>>(w_proj, wpT, 1024, 1024);

  gemm_bt_k<false><<<dim3(3072/128, 4096/128), 256, 0, stream>>>(xb, waT, b_attn, (void*)qkv, 4096, 3072, 1024);
  attn_k<<<dim3(SS/64, NHEADS, BB), 128, 0, stream>>>(qkv, aout);
  gemm_bt_k<true><<<dim3(1024/128, 4096/128), 256, 0, stream>>>(aout, wpT, b_proj, (void*)out, 4096, 1024, 1024);
}